// Round 10
// baseline (885.857 us; speedup 1.0000x reference)
//
#include <hip/hip_runtime.h>

#define TSTEPS 512
#define BATCH  64
#define DIN    256
#define DLAT   512

typedef _Float16 half8_t __attribute__((ext_vector_type(8)));
typedef float    f32x4  __attribute__((ext_vector_type(4)));

// d_ws layout: [0, 512K) = Wm, MFMA-fragment-packed fp16 W_h
#define WS_NEED (512u * 1024u)

// Barrier that waits ONLY on LDS ops (lgkmcnt), not on outstanding global
// stores. __syncthreads() emits s_waitcnt vmcnt(0) lgkmcnt(0) before
// s_barrier, which serially drains our per-step HBM result store (~400-900
// cyc dead time per step). The only cross-wave dependency at the step
// boundary is the hbuf LDS write -> lgkmcnt(0) suffices. sched_barrier(0)
// fences compiler motion around the asm (rule: hipcc can hoist reg-only ops
// past inline-asm waits).
__device__ __forceinline__ void barrier_lds_only()
{
    __builtin_amdgcn_sched_barrier(0);
    asm volatile("s_waitcnt lgkmcnt(0)\n\ts_barrier" ::: "memory");
    __builtin_amdgcn_sched_barrier(0);
}

// ---------------- Kernel A: P[m,n] = x[m,:] . W_in[n,:] + b_h[n] ----------------
#define BM 64
#define BN 64
#define BK 32

__global__ __launch_bounds__(256)
void precompute_gemm(const float* __restrict__ x,
                     const float* __restrict__ Win,
                     const float* __restrict__ bh,
                     float* __restrict__ P)
{
    __shared__ float As[BM][BK + 1];
    __shared__ float Ws[BN][BK + 1];
    const int m0  = blockIdx.y * BM;
    const int n0  = blockIdx.x * BN;
    const int tid = threadIdx.x;
    const int tx  = tid & 15;
    const int ty  = tid >> 4;
    const int lr  = tid >> 2;
    const int lc  = (tid & 3) * 8;

    float acc[4][4] = {};

    for (int kk = 0; kk < DIN; kk += BK) {
        const float* ax = x   + (size_t)(m0 + lr) * DIN + kk + lc;
        const float* aw = Win + (size_t)(n0 + lr) * DIN + kk + lc;
        float4 a0 = *(const float4*)(ax);
        float4 a1 = *(const float4*)(ax + 4);
        float4 w0 = *(const float4*)(aw);
        float4 w1 = *(const float4*)(aw + 4);
        As[lr][lc+0]=a0.x; As[lr][lc+1]=a0.y; As[lr][lc+2]=a0.z; As[lr][lc+3]=a0.w;
        As[lr][lc+4]=a1.x; As[lr][lc+5]=a1.y; As[lr][lc+6]=a1.z; As[lr][lc+7]=a1.w;
        Ws[lr][lc+0]=w0.x; Ws[lr][lc+1]=w0.y; Ws[lr][lc+2]=w0.z; Ws[lr][lc+3]=w0.w;
        Ws[lr][lc+4]=w1.x; Ws[lr][lc+5]=w1.y; Ws[lr][lc+6]=w1.z; Ws[lr][lc+7]=w1.w;
        __syncthreads();
        #pragma unroll
        for (int k = 0; k < BK; ++k) {
            float a[4], w[4];
            #pragma unroll
            for (int i = 0; i < 4; ++i) a[i] = As[ty*4+i][k];
            #pragma unroll
            for (int j = 0; j < 4; ++j) w[j] = Ws[tx*4+j][k];
            #pragma unroll
            for (int i = 0; i < 4; ++i)
                #pragma unroll
                for (int j = 0; j < 4; ++j)
                    acc[i][j] += a[i] * w[j];
        }
        __syncthreads();
    }

    float4 bv = *(const float4*)(bh + n0 + tx*4);
    #pragma unroll
    for (int i = 0; i < 4; ++i) {
        float4 v;
        v.x = acc[i][0] + bv.x; v.y = acc[i][1] + bv.y;
        v.z = acc[i][2] + bv.z; v.w = acc[i][3] + bv.w;
        *(float4*)(P + (size_t)(m0 + ty*4 + i) * DLAT + n0 + tx*4) = v;
    }
}

// -------- Pack W_h into MFMA B-fragment order (fp16) -----------------------------
// Tile (kt, ntg): 32 k x 16 n. Fragment element (lane, e) holds
// W_h[n = ntg*16 + (lane&15)][k = kt*32 + (lane>>4)*8 + e]. Stored flat:
// Wm[(tile*64 + lane)*8 + e], tile = kt*32 + ntg. The scan kernel loads A (h)
// with the SAME (lane>>4)*8+e k-formula, so any HW-internal k permutation
// cancels (dot over k is permutation-invariant). Verified on HW in R8/R9
// (absmax 0.03125).
__global__ __launch_bounds__(256)
void pack_wh_mfma(const float* __restrict__ Wh, _Float16* __restrict__ Wm)
{
    const int idx  = blockIdx.x * 256 + threadIdx.x;  // 32768 = 512 tiles x 64 lanes
    const int lane = idx & 63;
    const int tile = idx >> 6;
    const int kt   = tile >> 5;
    const int ntg  = tile & 31;
    const int n    = ntg * 16 + (lane & 15);
    const int k0   = kt * 32 + (lane >> 4) * 8;
    half8_t v;
    #pragma unroll
    for (int e = 0; e < 8; ++e)
        v[e] = (_Float16)Wh[(size_t)n * DLAT + k0 + e];
    *(half8_t*)(Wm + (size_t)idx * 8) = v;
}

// ---------------- Kernel B: MFMA scan, 8 waves, LDS-only step barrier -----------
// One chain per WG; 512 threads = 8 waves, 2 waves/SIMD (256-reg budget each).
// Wave w owns n-range [64w, 64w+64) = 4 n-tiles x 16 k-tiles = 64 MFMA/step.
// B-frags: f = kt*4+nt; f<46 in registers (AGPR overflow is read natively by
// MFMA - zero tax), f>=46 in LDS (144 KB, [frag][lane] b128 conflict-free).
// A = h broadcast (all 16 rows identical -> C rows identical). Epilogue: all
// 64 lanes, lane L owns n = 64w + L, value = C[L>>4][0]. Step barrier waits
// lgkmcnt only -> the HBM result store drains lazily instead of serializing
// every step (R9's ~850 cyc/step neither-pipe-busy window).
__global__ __launch_bounds__(512, 2)
void rnn_scan_mfma8(const half8_t* __restrict__ Wm,   // fragment-packed
                    const float* __restrict__ h0,
                    float* __restrict__ out)          // P in, h_seq out (in place)
{
    __shared__ half8_t  ldsB[8 * 18 * 64];   // 144 KB: [(w*18 + fl)*64 + lane]
    __shared__ _Float16 hbuf[2][DLAT];       // 2 KB, double-buffered h

    const int b    = blockIdx.x;
    const int tid  = threadIdx.x;
    const int w    = tid >> 6;               // wave 0..7: n-range 64w
    const int lane = tid & 63;

    // ---- one-time: B fragments into registers (f<46) and LDS (f>=46) ----
    // Wm tile index = kt*32 + ntg, ntg = w*4 + nt; f = kt*4 + nt.
    half8_t bfr[46];
    #pragma unroll
    for (int kt = 0; kt < 16; ++kt)
        #pragma unroll
        for (int nt = 0; nt < 4; ++nt) {
            const int f = kt * 4 + nt;
            half8_t v = Wm[(size_t)((kt * 32 + w * 4 + nt) * 64) + lane];
            if (f < 46) bfr[f] = v;
            else        ldsB[(w * 18 + (f - 46)) * 64 + lane] = v;
        }

    // ---- h(0) = h0 (pre-relu; negatives contribute) ----
    hbuf[0][tid] = (_Float16)h0[(size_t)b * DLAT + tid];
    __syncthreads();

    for (int t = 0; t < TSTEPS; ++t) {
        const int cur = t & 1, nxt = cur ^ 1;
        float* orow = out + ((size_t)t * BATCH + b) * DLAT;

        // prefetch P: lane L owns n = 64w + L (coalesced; hidden under MFMAs)
        float pv = orow[w * 64 + lane];

        f32x4 C[4] = {};
        #pragma unroll
        for (int kt = 0; kt < 16; ++kt) {
            // broadcast A: 16-lane groups read the same 16B h chunk
            half8_t A = *(const half8_t*)&hbuf[cur][kt * 32 + (lane >> 4) * 8];
            #pragma unroll
            for (int nt = 0; nt < 4; ++nt) {
                const int f = kt * 4 + nt;
                half8_t B = (f < 46) ? bfr[f]
                                     : ldsB[(w * 18 + (f - 46)) * 64 + lane];
                C[nt] = __builtin_amdgcn_mfma_f32_16x16x32_f16(A, B, C[nt], 0, 0, 0);
            }
        }

        // epilogue: all 64 lanes; lane L -> nt = L>>4, col = L&15, n = 64w + L
        const int g4 = lane >> 4;
        float m = (g4 == 0) ? C[0][0]
                : (g4 == 1) ? C[1][0]
                : (g4 == 2) ? C[2][0]
                :             C[3][0];     // all C rows equal (broadcast A)
        float v = fmaxf(m + pv, 0.f);
        orow[w * 64 + lane] = v;           // HBM store: drains lazily
        hbuf[nxt][w * 64 + lane] = (_Float16)v;
        barrier_lds_only();                // wait LDS only; not the HBM store
    }
}

// ---------------- Fallback (no workspace): row-major W_h, one row per thread ----
__global__ __launch_bounds__(512)
void rnn_scan_row(const float* __restrict__ Wh,
                  const float* __restrict__ h0,
                  float* __restrict__ out)
{
    __shared__ float h[DLAT];
    const int b = blockIdx.x;
    const int r = threadIdx.x;
    h[r] = h0[(size_t)b * DLAT + r];
    __syncthreads();
    const float* wrow = Wh + (size_t)r * DLAT;
    for (int t = 0; t < TSTEPS; ++t) {
        float* orow = out + ((size_t)t * BATCH + b) * DLAT;
        float acc = orow[r];
        #pragma unroll 8
        for (int k = 0; k < DLAT; k += 4) {
            float4 w  = *(const float4*)(wrow + k);
            float4 hv = *(const float4*)&h[k];
            acc += w.x*hv.x + w.y*hv.y + w.z*hv.z + w.w*hv.w;
        }
        float v = fmaxf(acc, 0.f);
        __syncthreads();
        h[r] = v;
        orow[r] = v;
        __syncthreads();
    }
}

extern "C" void kernel_launch(void* const* d_in, const int* in_sizes, int n_in,
                              void* d_out, int out_size, void* d_ws, size_t ws_size,
                              hipStream_t stream)
{
    const float* x    = (const float*)d_in[0];
    const float* h0   = (const float*)d_in[1];
    const float* Win  = (const float*)d_in[2];
    const float* Wh   = (const float*)d_in[3];
    const float* bh   = (const float*)d_in[4];
    float* out = (float*)d_out;

    dim3 gA(DLAT / BN, (TSTEPS * BATCH) / BM);   // (8, 512)
    precompute_gemm<<<gA, 256, 0, stream>>>(x, Win, bh, out);

    if (ws_size >= WS_NEED) {
        _Float16* Wm = (_Float16*)d_ws;
        pack_wh_mfma<<<128, 256, 0, stream>>>(Wh, Wm);
        rnn_scan_mfma8<<<BATCH, 512, 0, stream>>>((const half8_t*)Wm, h0, out);
    } else {
        rnn_scan_row<<<BATCH, 512, 0, stream>>>(Wh, h0, out);
    }
}

// Round 11
// 754.922 us; speedup vs baseline: 1.1734x; 1.1734x over previous
//
#include <hip/hip_runtime.h>

#define TSTEPS 512
#define BATCH  64
#define DIN    256
#define DLAT   512

typedef _Float16 half8_t __attribute__((ext_vector_type(8)));
typedef float    f32x4  __attribute__((ext_vector_type(4)));

// d_ws layout: [0, 512K) = Wm (scan W_h frags); [512K, 768K) = Wf (W_in frags)
#define WS_WF_OFF  (512u * 1024u)
#define WS_TIER2   (512u * 1024u)
#define WS_TIER1   (768u * 1024u)

// Barrier waiting only on LDS ops (lgkmcnt), not outstanding global stores.
__device__ __forceinline__ void barrier_lds_only()
{
    __builtin_amdgcn_sched_barrier(0);
    asm volatile("s_waitcnt lgkmcnt(0)\n\ts_barrier" ::: "memory");
    __builtin_amdgcn_sched_barrier(0);
}

// ---------------- Kernel A (tier2 fallback): fp32 tiled GEMM --------------------
#define BM 64
#define BN 64
#define BK 32

__global__ __launch_bounds__(256)
void precompute_gemm(const float* __restrict__ x,
                     const float* __restrict__ Win,
                     const float* __restrict__ bh,
                     float* __restrict__ P)
{
    __shared__ float As[BM][BK + 1];
    __shared__ float Ws[BN][BK + 1];
    const int m0  = blockIdx.y * BM;
    const int n0  = blockIdx.x * BN;
    const int tid = threadIdx.x;
    const int tx  = tid & 15;
    const int ty  = tid >> 4;
    const int lr  = tid >> 2;
    const int lc  = (tid & 3) * 8;

    float acc[4][4] = {};

    for (int kk = 0; kk < DIN; kk += BK) {
        const float* ax = x   + (size_t)(m0 + lr) * DIN + kk + lc;
        const float* aw = Win + (size_t)(n0 + lr) * DIN + kk + lc;
        float4 a0 = *(const float4*)(ax);
        float4 a1 = *(const float4*)(ax + 4);
        float4 w0 = *(const float4*)(aw);
        float4 w1 = *(const float4*)(aw + 4);
        As[lr][lc+0]=a0.x; As[lr][lc+1]=a0.y; As[lr][lc+2]=a0.z; As[lr][lc+3]=a0.w;
        As[lr][lc+4]=a1.x; As[lr][lc+5]=a1.y; As[lr][lc+6]=a1.z; As[lr][lc+7]=a1.w;
        Ws[lr][lc+0]=w0.x; Ws[lr][lc+1]=w0.y; Ws[lr][lc+2]=w0.z; Ws[lr][lc+3]=w0.w;
        Ws[lr][lc+4]=w1.x; Ws[lr][lc+5]=w1.y; Ws[lr][lc+6]=w1.z; Ws[lr][lc+7]=w1.w;
        __syncthreads();
        #pragma unroll
        for (int k = 0; k < BK; ++k) {
            float a[4], w[4];
            #pragma unroll
            for (int i = 0; i < 4; ++i) a[i] = As[ty*4+i][k];
            #pragma unroll
            for (int j = 0; j < 4; ++j) w[j] = Ws[tx*4+j][k];
            #pragma unroll
            for (int i = 0; i < 4; ++i)
                #pragma unroll
                for (int j = 0; j < 4; ++j)
                    acc[i][j] += a[i] * w[j];
        }
        __syncthreads();
    }

    float4 bv = *(const float4*)(bh + n0 + tx*4);
    #pragma unroll
    for (int i = 0; i < 4; ++i) {
        float4 v;
        v.x = acc[i][0] + bv.x; v.y = acc[i][1] + bv.y;
        v.z = acc[i][2] + bv.z; v.w = acc[i][3] + bv.w;
        *(float4*)(P + (size_t)(m0 + ty*4 + i) * DLAT + n0 + tx*4) = v;
    }
}

// -------- Pack W_h into MFMA B-fragment order (fp16) ----------------------------
// Tile (kt, ntg): 32 k x 16 n; element (lane, e) = W_h[ntg*16+(lane&15)]
// [kt*32+(lane>>4)*8+e]. Flat: Wm[(tile*64+lane)*8+e], tile = kt*32+ntg.
// Verified on HW R8-R10 (absmax 0.03125).
__global__ __launch_bounds__(256)
void pack_wh_mfma(const float* __restrict__ Wh, _Float16* __restrict__ Wm)
{
    const int idx  = blockIdx.x * 256 + threadIdx.x;  // 32768 = 512 tiles x 64
    const int lane = idx & 63;
    const int tile = idx >> 6;
    const int kt   = tile >> 5;
    const int ntg  = tile & 31;
    const int n    = ntg * 16 + (lane & 15);
    const int k0   = kt * 32 + (lane >> 4) * 8;
    half8_t v;
    #pragma unroll
    for (int e = 0; e < 8; ++e)
        v[e] = (_Float16)Wh[(size_t)n * DLAT + k0 + e];
    *(half8_t*)(Wm + (size_t)idx * 8) = v;
}

// -------- Pack W_in into MFMA B-fragment order (fp16), K = DIN = 256 ------------
// tile = kt*32 + ntg, kt in [0,8), ntg in [0,32).
__global__ __launch_bounds__(256)
void pack_win_f16(const float* __restrict__ Win, _Float16* __restrict__ Wf)
{
    const int idx  = blockIdx.x * 256 + threadIdx.x;  // 16384 = 256 tiles x 64
    const int lane = idx & 63;
    const int tile = idx >> 6;
    const int kt   = tile >> 5;
    const int ntg  = tile & 31;
    const int n    = ntg * 16 + (lane & 15);
    const int k0   = kt * 32 + (lane >> 4) * 8;
    half8_t v;
    #pragma unroll
    for (int e = 0; e < 8; ++e)
        v[e] = (_Float16)Win[(size_t)n * DIN + k0 + e];
    *(half8_t*)(Wf + (size_t)idx * 8) = v;
}

// ---------------- Kernel A (tier1): f16 MFMA GEMM  P = x @ Win^T + bh -----------
// Grid 1024 = 256 m-tiles x 4 n-tiles of 128x128; 256 thr = 4 waves (2x2 of
// 64x64). A-frags straight from global x (lane reads 32B of one row; 4 lanes
// share a 128B line - coalesced enough, L3 absorbs the 4x N-reuse). B-frags
// from packed Wf (256 KB, L2-hot). C mapping (m89-verified): col = lane&15,
// row = (lane>>4)*4 + r.
__global__ __launch_bounds__(256)
void precompute_mfma(const float* __restrict__ x,
                     const half8_t* __restrict__ Wf,
                     const float* __restrict__ bh,
                     float* __restrict__ P)
{
    const int tid  = threadIdx.x;
    const int wave = tid >> 6, lane = tid & 63;
    const int wm   = wave >> 1, wn = wave & 1;
    const int m0   = (blockIdx.x >> 2) * 128 + wm * 64;
    const int n0   = (blockIdx.x & 3) * 128 + wn * 64;
    const int col  = lane & 15, rg = lane >> 4;

    float bv[4];
    #pragma unroll
    for (int nt = 0; nt < 4; ++nt) bv[nt] = bh[n0 + nt * 16 + col];

    f32x4 C[4][4] = {};

    #pragma unroll
    for (int kt = 0; kt < 8; ++kt) {
        half8_t A[4];
        #pragma unroll
        for (int mt = 0; mt < 4; ++mt) {
            const float* xp = x + (size_t)(m0 + mt * 16 + col) * DIN
                                + kt * 32 + rg * 8;
            float4 a = *(const float4*)xp;
            float4 b = *(const float4*)(xp + 4);
            half8_t v;
            v[0] = (_Float16)a.x; v[1] = (_Float16)a.y;
            v[2] = (_Float16)a.z; v[3] = (_Float16)a.w;
            v[4] = (_Float16)b.x; v[5] = (_Float16)b.y;
            v[6] = (_Float16)b.z; v[7] = (_Float16)b.w;
            A[mt] = v;
        }
        half8_t B[4];
        #pragma unroll
        for (int nt = 0; nt < 4; ++nt)
            B[nt] = Wf[(size_t)((kt * 32 + (n0 >> 4) + nt) * 64) + lane];
        #pragma unroll
        for (int mt = 0; mt < 4; ++mt)
            #pragma unroll
            for (int nt = 0; nt < 4; ++nt)
                C[mt][nt] = __builtin_amdgcn_mfma_f32_16x16x32_f16(
                                A[mt], B[nt], C[mt][nt], 0, 0, 0);
    }

    #pragma unroll
    for (int mt = 0; mt < 4; ++mt)
        #pragma unroll
        for (int nt = 0; nt < 4; ++nt) {
            #pragma unroll
            for (int r = 0; r < 4; ++r) {
                const int m = m0 + mt * 16 + rg * 4 + r;
                P[(size_t)m * DLAT + n0 + nt * 16 + col] = C[mt][nt][r] + bv[nt];
            }
        }
}

// ---------------- Kernel B: MFMA scan, 8 waves, 50 reg-frags --------------------
// One chain per WG; 512 threads = 8 waves, 2 waves/SIMD. Wave w owns n-range
// [64w, 64w+64) = 4 nt x 16 kt = 64 MFMA/step. B-frags f = kt*4+nt: f<50 in
// registers (200 regs; AGPR overflow read natively by MFMA), f>=50 in LDS
// (14 frags x 8 waves = 112 KB). LDS instrs/wave/step: 16 A + 14 B = 30
// (was 34) - the measured wall is the LDS instruction pipe (~12 cyc/b128).
// A = h broadcast (all 16 rows identical). Epilogue: lane L owns n = 64w+L.
__global__ __launch_bounds__(512, 2)
void rnn_scan_mfma8(const half8_t* __restrict__ Wm,   // fragment-packed
                    const float* __restrict__ h0,
                    float* __restrict__ out)          // P in, h_seq out (in place)
{
    __shared__ half8_t  ldsB[8 * 14 * 64];   // 112 KB: [(w*14 + slot)*64 + lane]
    __shared__ _Float16 hbuf[2][DLAT];       // 2 KB, double-buffered h

    const int b    = blockIdx.x;
    const int tid  = threadIdx.x;
    const int w    = tid >> 6;               // wave 0..7: n-range 64w
    const int lane = tid & 63;

    // ---- one-time: B fragments into registers (f<50) and LDS (f>=50) ----
    half8_t bfr[50];
    #pragma unroll
    for (int kt = 0; kt < 16; ++kt)
        #pragma unroll
        for (int nt = 0; nt < 4; ++nt) {
            const int f = kt * 4 + nt;
            half8_t v = Wm[(size_t)((kt * 32 + w * 4 + nt) * 64) + lane];
            if (f < 50) bfr[f] = v;
            else        ldsB[(w * 14 + (f - 50)) * 64 + lane] = v;
        }

    // ---- h(0) = h0 (pre-relu; negatives contribute) ----
    hbuf[0][tid] = (_Float16)h0[(size_t)b * DLAT + tid];
    __syncthreads();

    for (int t = 0; t < TSTEPS; ++t) {
        const int cur = t & 1, nxt = cur ^ 1;
        float* orow = out + ((size_t)t * BATCH + b) * DLAT;

        // prefetch P: lane L owns n = 64w + L (coalesced; hidden under MFMAs)
        float pv = orow[w * 64 + lane];

        f32x4 C[4] = {};
        #pragma unroll
        for (int kt = 0; kt < 16; ++kt) {
            // broadcast A: 16-lane groups read the same 16B h chunk
            half8_t A = *(const half8_t*)&hbuf[cur][kt * 32 + (lane >> 4) * 8];
            #pragma unroll
            for (int nt = 0; nt < 4; ++nt) {
                const int f = kt * 4 + nt;
                half8_t B = (f < 50) ? bfr[f]
                                     : ldsB[(w * 14 + (f - 50)) * 64 + lane];
                C[nt] = __builtin_amdgcn_mfma_f32_16x16x32_f16(A, B, C[nt], 0, 0, 0);
            }
        }

        // epilogue: all 64 lanes; lane L -> nt = L>>4, col = L&15, n = 64w + L
        const int g4 = lane >> 4;
        float m = (g4 == 0) ? C[0][0]
                : (g4 == 1) ? C[1][0]
                : (g4 == 2) ? C[2][0]
                :             C[3][0];     // all C rows equal (broadcast A)
        float v = fmaxf(m + pv, 0.f);
        orow[w * 64 + lane] = v;           // HBM store: drains lazily
        hbuf[nxt][w * 64 + lane] = (_Float16)v;
        barrier_lds_only();                // wait LDS only; not the HBM store
    }
}

// ---------------- Fallback (no workspace): row-major W_h, one row per thread ----
__global__ __launch_bounds__(512)
void rnn_scan_row(const float* __restrict__ Wh,
                  const float* __restrict__ h0,
                  float* __restrict__ out)
{
    __shared__ float h[DLAT];
    const int b = blockIdx.x;
    const int r = threadIdx.x;
    h[r] = h0[(size_t)b * DLAT + r];
    __syncthreads();
    const float* wrow = Wh + (size_t)r * DLAT;
    for (int t = 0; t < TSTEPS; ++t) {
        float* orow = out + ((size_t)t * BATCH + b) * DLAT;
        float acc = orow[r];
        #pragma unroll 8
        for (int k = 0; k < DLAT; k += 4) {
            float4 w  = *(const float4*)(wrow + k);
            float4 hv = *(const float4*)&h[k];
            acc += w.x*hv.x + w.y*hv.y + w.z*hv.z + w.w*hv.w;
        }
        float v = fmaxf(acc, 0.f);
        __syncthreads();
        h[r] = v;
        orow[r] = v;
        __syncthreads();
    }
}

extern "C" void kernel_launch(void* const* d_in, const int* in_sizes, int n_in,
                              void* d_out, int out_size, void* d_ws, size_t ws_size,
                              hipStream_t stream)
{
    const float* x    = (const float*)d_in[0];
    const float* h0   = (const float*)d_in[1];
    const float* Win  = (const float*)d_in[2];
    const float* Wh   = (const float*)d_in[3];
    const float* bh   = (const float*)d_in[4];
    float* out = (float*)d_out;

    if (ws_size >= WS_TIER1) {
        _Float16* Wm = (_Float16*)d_ws;
        _Float16* Wf = (_Float16*)((char*)d_ws + WS_WF_OFF);
        pack_wh_mfma<<<128, 256, 0, stream>>>(Wh, Wm);
        pack_win_f16<<<64, 256, 0, stream>>>(Win, Wf);
        precompute_mfma<<<1024, 256, 0, stream>>>(x, (const half8_t*)Wf, bh, out);
        rnn_scan_mfma8<<<BATCH, 512, 0, stream>>>((const half8_t*)Wm, h0, out);
    } else if (ws_size >= WS_TIER2) {
        _Float16* Wm = (_Float16*)d_ws;
        dim3 gA(DLAT / BN, (TSTEPS * BATCH) / BM);   // (8, 512)
        pack_wh_mfma<<<128, 256, 0, stream>>>(Wh, Wm);
        precompute_gemm<<<gA, 256, 0, stream>>>(x, Win, bh, out);
        rnn_scan_mfma8<<<BATCH, 512, 0, stream>>>((const half8_t*)Wm, h0, out);
    } else {
        dim3 gA(DLAT / BN, (TSTEPS * BATCH) / BM);
        precompute_gemm<<<gA, 256, 0, stream>>>(x, Win, bh, out);
        rnn_scan_row<<<BATCH, 512, 0, stream>>>(Wh, h0, out);
    }
}